// Round 1
// baseline (411.841 us; speedup 1.0000x reference)
//
#include <hip/hip_runtime.h>
#include <hip/hip_bf16.h>
#include <stdint.h>

typedef __bf16 bf16;
typedef __bf16 bf16x8 __attribute__((ext_vector_type(8)));
typedef __bf16 bf16x4 __attribute__((ext_vector_type(4)));
typedef float f32x4 __attribute__((ext_vector_type(4)));

#define F_DIM 1024
#define NSEQ  2048
#define NB    4
#define NH    16
#define HD    64
#define MROWS (NB * NSEQ)  /* 8192 */

__device__ __forceinline__ void gload_lds16(const void* g, void* l) {
    __builtin_amdgcn_global_load_lds(
        (__attribute__((address_space(1))) void*)g,
        (__attribute__((address_space(3))) void*)l,
        16, 0, 0);
}

// ---------------------------------------------------------------------------
// Fused double layernorm: xn = LN(x)*g1+b1, cn = LN(x)*g2+b2 (shared mu/var)
// one block per row (1024 floats), 256 threads, float4 per thread
// ---------------------------------------------------------------------------
__global__ __launch_bounds__(256) void ln2_kernel(
    const float* __restrict__ x,
    const float* __restrict__ g1, const float* __restrict__ b1,
    const float* __restrict__ g2, const float* __restrict__ b2,
    bf16* __restrict__ xn, bf16* __restrict__ cn)
{
    const int row = blockIdx.x;
    const int t = threadIdx.x;
    float4 v = reinterpret_cast<const float4*>(x + (size_t)row * F_DIM)[t];
    float s  = v.x + v.y + v.z + v.w;
    float ss = v.x * v.x + v.y * v.y + v.z * v.z + v.w * v.w;
#pragma unroll
    for (int m = 1; m < 64; m <<= 1) {
        s  += __shfl_xor(s, m);
        ss += __shfl_xor(ss, m);
    }
    __shared__ float red[8];
    const int w = t >> 6;
    if ((t & 63) == 0) { red[w] = s; red[4 + w] = ss; }
    __syncthreads();
    s  = red[0] + red[1] + red[2] + red[3];
    ss = red[4] + red[5] + red[6] + red[7];
    const float mu  = s * (1.0f / F_DIM);
    const float var = fmaxf(ss * (1.0f / F_DIM) - mu * mu, 0.0f);
    const float rs  = rsqrtf(var + 1e-5f);

    float4 G1 = reinterpret_cast<const float4*>(g1)[t];
    float4 B1 = reinterpret_cast<const float4*>(b1)[t];
    float4 G2 = reinterpret_cast<const float4*>(g2)[t];
    float4 B2 = reinterpret_cast<const float4*>(b2)[t];
    const float h0 = (v.x - mu) * rs, h1 = (v.y - mu) * rs;
    const float h2 = (v.z - mu) * rs, h3 = (v.w - mu) * rs;
    bf16x4 o1 = { (bf16)(h0 * G1.x + B1.x), (bf16)(h1 * G1.y + B1.y),
                  (bf16)(h2 * G1.z + B1.z), (bf16)(h3 * G1.w + B1.w) };
    bf16x4 o2 = { (bf16)(h0 * G2.x + B2.x), (bf16)(h1 * G2.y + B2.y),
                  (bf16)(h2 * G2.z + B2.z), (bf16)(h3 * G2.w + B2.w) };
    *reinterpret_cast<bf16x4*>(xn + (size_t)row * F_DIM + t * 4) = o1;
    *reinterpret_cast<bf16x4*>(cn + (size_t)row * F_DIM + t * 4) = o2;
}

// ---------------------------------------------------------------------------
// fp32 -> bf16 convert (for weights)
// ---------------------------------------------------------------------------
__global__ __launch_bounds__(256) void cvt_kernel(
    const float* __restrict__ src, bf16* __restrict__ dst, int n4)
{
    int i = blockIdx.x * 256 + threadIdx.x;
    if (i < n4) {
        float4 v = reinterpret_cast<const float4*>(src)[i];
        bf16x4 o = { (bf16)v.x, (bf16)v.y, (bf16)v.z, (bf16)v.w };
        reinterpret_cast<bf16x4*>(dst)[i] = o;
    }
}

// ---------------------------------------------------------------------------
// GEMM: C[M,N] = A[M,K] * B[N,K]^T   (both row-major bf16, K%32==0)
// 128x128 tile, BK=32, 4 waves (2x2), each wave 64x64 via 4x4 16x16x32 MFMAs.
// EPI==0: store bf16 C.  EPI==1: store fp32 C = acc + skip.
// ---------------------------------------------------------------------------
template <int EPI>
__global__ __launch_bounds__(256, 2) void gemm_bt(
    const bf16* __restrict__ A, const bf16* __restrict__ B,
    bf16* __restrict__ Cb, float* __restrict__ Cf,
    const float* __restrict__ skip, int M, int N, int K)
{
    __shared__ bf16 As[128 * 32];
    __shared__ bf16 Bs[128 * 32];
    const int t = threadIdx.x;
    const int lane = t & 63;
    const int w = t >> 6;
    const int wr = w >> 1, wc = w & 1;
    const int bm = blockIdx.y * 128;
    const int bn = blockIdx.x * 128;
    const int r = lane & 15;
    const int kg = (lane >> 4) * 8;

    f32x4 acc[4][4];
#pragma unroll
    for (int i = 0; i < 4; i++)
#pragma unroll
        for (int j = 0; j < 4; j++) acc[i][j] = (f32x4){0.f, 0.f, 0.f, 0.f};

    // staging: tile = 128 rows x 32 cols bf16 = 512 x 16B chunks; chunk c -> row c>>2, col (c&3)*8
    const int c0 = t, c1 = 256 + t;
    const size_t aoff0 = (size_t)(bm + (c0 >> 2)) * K + (c0 & 3) * 8;
    const size_t aoff1 = (size_t)(bm + (c1 >> 2)) * K + (c1 & 3) * 8;
    const size_t boff0 = (size_t)(bn + (c0 >> 2)) * K + (c0 & 3) * 8;
    const size_t boff1 = (size_t)(bn + (c1 >> 2)) * K + (c1 & 3) * 8;
    bf16* lA0 = As + (size_t)(0 * 256 + w * 64) * 8;
    bf16* lA1 = As + (size_t)(1 * 256 + w * 64) * 8;
    bf16* lB0 = Bs + (size_t)(0 * 256 + w * 64) * 8;
    bf16* lB1 = Bs + (size_t)(1 * 256 + w * 64) * 8;

    for (int kt = 0; kt < K; kt += 32) {
        gload_lds16(A + aoff0 + kt, lA0);
        gload_lds16(A + aoff1 + kt, lA1);
        gload_lds16(B + boff0 + kt, lB0);
        gload_lds16(B + boff1 + kt, lB1);
        __syncthreads();
        bf16x8 af[4], bfr[4];
#pragma unroll
        for (int mi = 0; mi < 4; mi++)
            af[mi] = *(const bf16x8*)(As + (wr * 64 + mi * 16 + r) * 32 + kg);
#pragma unroll
        for (int ni = 0; ni < 4; ni++)
            bfr[ni] = *(const bf16x8*)(Bs + (wc * 64 + ni * 16 + r) * 32 + kg);
#pragma unroll
        for (int mi = 0; mi < 4; mi++)
#pragma unroll
            for (int ni = 0; ni < 4; ni++)
                acc[mi][ni] = __builtin_amdgcn_mfma_f32_16x16x32_bf16(
                    af[mi], bfr[ni], acc[mi][ni], 0, 0, 0);
        __syncthreads();
    }

    const int g = lane >> 4;
#pragma unroll
    for (int mi = 0; mi < 4; mi++) {
#pragma unroll
        for (int ni = 0; ni < 4; ni++) {
            const int col = bn + wc * 64 + ni * 16 + r;
#pragma unroll
            for (int j = 0; j < 4; j++) {
                const int row = bm + wr * 64 + mi * 16 + g * 4 + j;
                const float vv = acc[mi][ni][j];
                if (EPI == 0) {
                    Cb[(size_t)row * N + col] = (bf16)vv;
                } else {
                    Cf[(size_t)row * N + col] = vv + skip[(size_t)row * N + col];
                }
            }
        }
    }
}

// ---------------------------------------------------------------------------
// Flash attention, bf16 MFMA. grid (N/64, B*H), 256 thr = 4 waves.
// Wave handles 16 q-rows; KV tiles of 64. q:[8192][1024] h-major cols,
// kv:[8192][2048] (K cols 0..1023, V cols 1024..2047). out bf16 [8192][1024].
// ---------------------------------------------------------------------------
__global__ __launch_bounds__(256, 2) void attn_kernel(
    const bf16* __restrict__ q, const bf16* __restrict__ kv,
    bf16* __restrict__ o)
{
    const int qt = blockIdx.x;
    const int bh = blockIdx.y;
    const int b = bh >> 4, h = bh & 15;
    const int t = threadIdx.x, lane = t & 63, w = t >> 6;
    const int r = lane & 15, g = lane >> 4;

    const size_t qbase  = (size_t)b * NSEQ * F_DIM + h * HD;
    const size_t kvbase = (size_t)b * NSEQ * (2 * F_DIM) + h * HD;
    const size_t vbase  = kvbase + F_DIM;

    __shared__ bf16 Vt[64 * 72];        // [d][kv] transposed V tile, stride 72
    __shared__ bf16 Ps[4][16 * 72];     // per-wave P tile [qrow][kv], stride 72

    const int q0 = qt * 64 + w * 16;
    bf16x8 qf[2];
#pragma unroll
    for (int kk = 0; kk < 2; kk++)
        qf[kk] = *(const bf16x8*)(q + qbase + (size_t)(q0 + r) * F_DIM + kk * 32 + g * 8);

    f32x4 oacc[4];
#pragma unroll
    for (int i = 0; i < 4; i++) oacc[i] = (f32x4){0.f, 0.f, 0.f, 0.f};
    float mrow[4], lrow[4];
#pragma unroll
    for (int i = 0; i < 4; i++) { mrow[i] = -1e30f; lrow[i] = 0.f; }

    for (int kv0 = 0; kv0 < NSEQ; kv0 += 64) {
        __syncthreads();  // previous PV done reading Vt
        // stage V^T: thread reads 8 consecutive d of one kv row, scatters to Vt[d][kv]
#pragma unroll
        for (int it = 0; it < 2; ++it) {
            const int kvr = it * 32 + (t >> 3);
            const int dc = (t & 7) * 8;
            bf16x8 vv = *(const bf16x8*)(kv + vbase + (size_t)(kv0 + kvr) * (2 * F_DIM) + dc);
#pragma unroll
            for (int j = 0; j < 8; j++) Vt[(dc + j) * 72 + kvr] = vv[j];
        }
        // S = Q K^T (K fragments straight from global: B^T form)
        f32x4 s[4];
#pragma unroll
        for (int nt = 0; nt < 4; nt++) {
            s[nt] = (f32x4){0.f, 0.f, 0.f, 0.f};
#pragma unroll
            for (int kk = 0; kk < 2; kk++) {
                bf16x8 kf = *(const bf16x8*)(kv + kvbase +
                    (size_t)(kv0 + nt * 16 + r) * (2 * F_DIM) + kk * 32 + g * 8);
                s[nt] = __builtin_amdgcn_mfma_f32_16x16x32_bf16(qf[kk], kf, s[nt], 0, 0, 0);
            }
        }
#pragma unroll
        for (int nt = 0; nt < 4; nt++) s[nt] *= 0.125f;

        // online softmax for rows g*4+j (cols spread over r-lanes and nt)
        float alpha[4];
#pragma unroll
        for (int j = 0; j < 4; j++) {
            float mx = fmaxf(fmaxf(s[0][j], s[1][j]), fmaxf(s[2][j], s[3][j]));
#pragma unroll
            for (int msk = 1; msk < 16; msk <<= 1) mx = fmaxf(mx, __shfl_xor(mx, msk));
            const float mnew = fmaxf(mrow[j], mx);
            alpha[j] = __expf(mrow[j] - mnew);
            mrow[j] = mnew;
            float psum = 0.f;
#pragma unroll
            for (int nt = 0; nt < 4; nt++) {
                const float p = __expf(s[nt][j] - mnew);
                s[nt][j] = p;
                psum += p;
            }
#pragma unroll
            for (int msk = 1; msk < 16; msk <<= 1) psum += __shfl_xor(psum, msk);
            lrow[j] = lrow[j] * alpha[j] + psum;
        }
        // P -> LDS (per-wave region)
#pragma unroll
        for (int nt = 0; nt < 4; nt++)
#pragma unroll
            for (int j = 0; j < 4; j++)
                Ps[w][(g * 4 + j) * 72 + nt * 16 + r] = (bf16)s[nt][j];
        __syncthreads();  // Vt fully staged
        // rescale O
#pragma unroll
        for (int nt = 0; nt < 4; nt++)
#pragma unroll
            for (int j = 0; j < 4; j++) oacc[nt][j] *= alpha[j];
        // O += P * V
        bf16x8 pa[2];
#pragma unroll
        for (int kk = 0; kk < 2; kk++)
            pa[kk] = *(const bf16x8*)(&Ps[w][r * 72 + kk * 32 + g * 8]);
#pragma unroll
        for (int nt = 0; nt < 4; nt++) {
#pragma unroll
            for (int kk = 0; kk < 2; kk++) {
                bf16x8 vb = *(const bf16x8*)(&Vt[(nt * 16 + r) * 72 + kk * 32 + g * 8]);
                oacc[nt] = __builtin_amdgcn_mfma_f32_16x16x32_bf16(pa[kk], vb, oacc[nt], 0, 0, 0);
            }
        }
    }
    // epilogue: normalize + store
#pragma unroll
    for (int nt = 0; nt < 4; nt++) {
#pragma unroll
        for (int j = 0; j < 4; j++) {
            const int row = q0 + g * 4 + j;
            const int d = nt * 16 + r;
            o[(size_t)(b * NSEQ + row) * F_DIM + h * HD + d] =
                (bf16)(oacc[nt][j] / lrow[j]);
        }
    }
}

// ---------------------------------------------------------------------------
extern "C" void kernel_launch(void* const* d_in, const int* in_sizes, int n_in,
                              void* d_out, int out_size, void* d_ws, size_t ws_size,
                              hipStream_t stream)
{
    const float* x     = (const float*)d_in[0];
    const float* Wq    = (const float*)d_in[1];
    const float* Wkv   = (const float*)d_in[2];
    const float* Wo    = (const float*)d_in[3];
    const float* ln_g  = (const float*)d_in[4];
    const float* ln_b  = (const float*)d_in[5];
    const float* lnc_g = (const float*)d_in[6];
    const float* lnc_b = (const float*)d_in[7];
    float* out = (float*)d_out;

    bf16* xn   = (bf16*)d_ws;                                   // 16.78 MB
    bf16* cn   = xn  + (size_t)MROWS * F_DIM;                   // 16.78 MB
    bf16* qb   = cn  + (size_t)MROWS * F_DIM;                   // 16.78 MB
    bf16* kvb  = qb  + (size_t)MROWS * F_DIM;                   // 33.55 MB
    bf16* wqb  = kvb + (size_t)MROWS * 2 * F_DIM;               // 2.1 MB
    bf16* wkvb = wqb + (size_t)F_DIM * F_DIM;                   // 4.2 MB
    bf16* wob  = wkvb + (size_t)2 * F_DIM * F_DIM;              // 2.1 MB
    bf16* ao   = xn;  // reuse: xn dead after q-GEMM, attention runs later

    ln2_kernel<<<dim3(MROWS), dim3(256), 0, stream>>>(x, ln_g, ln_b, lnc_g, lnc_b, xn, cn);

    cvt_kernel<<<dim3((F_DIM * F_DIM / 4 + 255) / 256), dim3(256), 0, stream>>>(Wq, wqb, F_DIM * F_DIM / 4);
    cvt_kernel<<<dim3((2 * F_DIM * F_DIM / 4 + 255) / 256), dim3(256), 0, stream>>>(Wkv, wkvb, 2 * F_DIM * F_DIM / 4);
    cvt_kernel<<<dim3((F_DIM * F_DIM / 4 + 255) / 256), dim3(256), 0, stream>>>(Wo, wob, F_DIM * F_DIM / 4);

    // q = xn * Wq^T   [8192 x 1024]
    gemm_bt<0><<<dim3(F_DIM / 128, MROWS / 128), dim3(256), 0, stream>>>(
        xn, wqb, qb, nullptr, nullptr, MROWS, F_DIM, F_DIM);
    // kv = cn * Wkv^T [8192 x 2048]
    gemm_bt<0><<<dim3(2 * F_DIM / 128, MROWS / 128), dim3(256), 0, stream>>>(
        cn, wkvb, kvb, nullptr, nullptr, MROWS, 2 * F_DIM, F_DIM);
    // attention
    attn_kernel<<<dim3(NSEQ / 64, NB * NH), dim3(256), 0, stream>>>(qb, kvb, ao);
    // out = ao * Wo^T + x  [fp32]
    gemm_bt<1><<<dim3(F_DIM / 128, MROWS / 128), dim3(256), 0, stream>>>(
        ao, wob, nullptr, out, x, MROWS, F_DIM, F_DIM);
}

// Round 3
// 258.861 us; speedup vs baseline: 1.5910x; 1.5910x over previous
//
#include <hip/hip_runtime.h>
#include <hip/hip_bf16.h>
#include <stdint.h>

typedef __bf16 bf16;
typedef __bf16 bf16x8 __attribute__((ext_vector_type(8)));
typedef __bf16 bf16x4 __attribute__((ext_vector_type(4)));
typedef float f32x4 __attribute__((ext_vector_type(4)));
typedef unsigned u32x2 __attribute__((ext_vector_type(2)));

#define F_DIM 1024
#define NSEQ  2048
#define NB    4
#define NH    16
#define HD    64
#define MROWS (NB * NSEQ)  /* 8192 */

__device__ __forceinline__ void gload_lds16(const void* g, void* l) {
    __builtin_amdgcn_global_load_lds(
        (__attribute__((address_space(1))) void*)g,
        (__attribute__((address_space(3))) void*)l,
        16, 0, 0);
}

__device__ __forceinline__ unsigned lds_addr(const void* p) {
    return (unsigned)(size_t)(__attribute__((address_space(3))) const void*)p;
}

// ---------------------------------------------------------------------------
// Fused double layernorm: xn = LN(x)*g1+b1, cn = LN(x)*g2+b2 (shared mu/var)
// ---------------------------------------------------------------------------
__global__ __launch_bounds__(256) void ln2_kernel(
    const float* __restrict__ x,
    const float* __restrict__ g1, const float* __restrict__ b1,
    const float* __restrict__ g2, const float* __restrict__ b2,
    bf16* __restrict__ xn, bf16* __restrict__ cn)
{
    const int row = blockIdx.x;
    const int t = threadIdx.x;
    float4 v = reinterpret_cast<const float4*>(x + (size_t)row * F_DIM)[t];
    float s  = v.x + v.y + v.z + v.w;
    float ss = v.x * v.x + v.y * v.y + v.z * v.z + v.w * v.w;
#pragma unroll
    for (int m = 1; m < 64; m <<= 1) {
        s  += __shfl_xor(s, m);
        ss += __shfl_xor(ss, m);
    }
    __shared__ float red[8];
    const int w = t >> 6;
    if ((t & 63) == 0) { red[w] = s; red[4 + w] = ss; }
    __syncthreads();
    s  = red[0] + red[1] + red[2] + red[3];
    ss = red[4] + red[5] + red[6] + red[7];
    const float mu  = s * (1.0f / F_DIM);
    const float var = fmaxf(ss * (1.0f / F_DIM) - mu * mu, 0.0f);
    const float rs  = rsqrtf(var + 1e-5f);

    float4 G1 = reinterpret_cast<const float4*>(g1)[t];
    float4 B1 = reinterpret_cast<const float4*>(b1)[t];
    float4 G2 = reinterpret_cast<const float4*>(g2)[t];
    float4 B2 = reinterpret_cast<const float4*>(b2)[t];
    const float h0 = (v.x - mu) * rs, h1 = (v.y - mu) * rs;
    const float h2 = (v.z - mu) * rs, h3 = (v.w - mu) * rs;
    bf16x4 o1 = { (bf16)(h0 * G1.x + B1.x), (bf16)(h1 * G1.y + B1.y),
                  (bf16)(h2 * G1.z + B1.z), (bf16)(h3 * G1.w + B1.w) };
    bf16x4 o2 = { (bf16)(h0 * G2.x + B2.x), (bf16)(h1 * G2.y + B2.y),
                  (bf16)(h2 * G2.z + B2.z), (bf16)(h3 * G2.w + B2.w) };
    *reinterpret_cast<bf16x4*>(xn + (size_t)row * F_DIM + t * 4) = o1;
    *reinterpret_cast<bf16x4*>(cn + (size_t)row * F_DIM + t * 4) = o2;
}

// ---------------------------------------------------------------------------
__global__ __launch_bounds__(256) void cvt_kernel(
    const float* __restrict__ src, bf16* __restrict__ dst, int n4)
{
    int i = blockIdx.x * 256 + threadIdx.x;
    if (i < n4) {
        float4 v = reinterpret_cast<const float4*>(src)[i];
        bf16x4 o = { (bf16)v.x, (bf16)v.y, (bf16)v.z, (bf16)v.w };
        reinterpret_cast<bf16x4*>(dst)[i] = o;
    }
}

// ---------------------------------------------------------------------------
// GEMM: C[M,N] = A[M,K] * B[N,K]^T. EPI==0: bf16 C = acc*oscale. EPI==1: fp32 C = acc+skip.
// ---------------------------------------------------------------------------
template <int EPI>
__global__ __launch_bounds__(256, 2) void gemm_bt(
    const bf16* __restrict__ A, const bf16* __restrict__ B,
    bf16* __restrict__ Cb, float* __restrict__ Cf,
    const float* __restrict__ skip, int M, int N, int K, float oscale)
{
    __shared__ bf16 As[128 * 32];
    __shared__ bf16 Bs[128 * 32];
    const int t = threadIdx.x;
    const int lane = t & 63;
    const int w = t >> 6;
    const int wr = w >> 1, wc = w & 1;
    const int bm = blockIdx.y * 128;
    const int bn = blockIdx.x * 128;
    const int r = lane & 15;
    const int kg = (lane >> 4) * 8;

    f32x4 acc[4][4];
#pragma unroll
    for (int i = 0; i < 4; i++)
#pragma unroll
        for (int j = 0; j < 4; j++) acc[i][j] = (f32x4){0.f, 0.f, 0.f, 0.f};

    const int c0 = t, c1 = 256 + t;
    const size_t aoff0 = (size_t)(bm + (c0 >> 2)) * K + (c0 & 3) * 8;
    const size_t aoff1 = (size_t)(bm + (c1 >> 2)) * K + (c1 & 3) * 8;
    const size_t boff0 = (size_t)(bn + (c0 >> 2)) * K + (c0 & 3) * 8;
    const size_t boff1 = (size_t)(bn + (c1 >> 2)) * K + (c1 & 3) * 8;
    bf16* lA0 = As + (size_t)(0 * 256 + w * 64) * 8;
    bf16* lA1 = As + (size_t)(1 * 256 + w * 64) * 8;
    bf16* lB0 = Bs + (size_t)(0 * 256 + w * 64) * 8;
    bf16* lB1 = Bs + (size_t)(1 * 256 + w * 64) * 8;

    for (int kt = 0; kt < K; kt += 32) {
        gload_lds16(A + aoff0 + kt, lA0);
        gload_lds16(A + aoff1 + kt, lA1);
        gload_lds16(B + boff0 + kt, lB0);
        gload_lds16(B + boff1 + kt, lB1);
        __syncthreads();
        bf16x8 af[4], bfr[4];
#pragma unroll
        for (int mi = 0; mi < 4; mi++)
            af[mi] = *(const bf16x8*)(As + (wr * 64 + mi * 16 + r) * 32 + kg);
#pragma unroll
        for (int ni = 0; ni < 4; ni++)
            bfr[ni] = *(const bf16x8*)(Bs + (wc * 64 + ni * 16 + r) * 32 + kg);
#pragma unroll
        for (int mi = 0; mi < 4; mi++)
#pragma unroll
            for (int ni = 0; ni < 4; ni++)
                acc[mi][ni] = __builtin_amdgcn_mfma_f32_16x16x32_bf16(
                    af[mi], bfr[ni], acc[mi][ni], 0, 0, 0);
        __syncthreads();
    }

    const int g = lane >> 4;
#pragma unroll
    for (int mi = 0; mi < 4; mi++) {
#pragma unroll
        for (int ni = 0; ni < 4; ni++) {
            const int col = bn + wc * 64 + ni * 16 + r;
#pragma unroll
            for (int j = 0; j < 4; j++) {
                const int row = bm + wr * 64 + mi * 16 + g * 4 + j;
                const float vv = acc[mi][ni][j];
                if (EPI == 0) {
                    Cb[(size_t)row * N + col] = (bf16)(vv * oscale);
                } else {
                    Cf[(size_t)row * N + col] = vv + skip[(size_t)row * N + col];
                }
            }
        }
    }
}

// ---------------------------------------------------------------------------
// Flash attention v3: swapped QK^T (lane-parallel softmax), K via XOR-swizzled
// global_load_lds, V via [kvb][dblk][4][16]-subtiled global_load_lds consumed
// by per-lane-addressed ds_read_b64_tr_b16 (lane r gets d-column r, 4 kv elems).
// grid 2048 blocks (XCD-chunked), 256 thr = 4 waves, wave = 16 q-rows, KV tile 64.
// q pre-scaled by 0.125 in the q-GEMM epilogue.
// ---------------------------------------------------------------------------
__global__ __launch_bounds__(256, 4) void attn_kernel(
    const bf16* __restrict__ q, const bf16* __restrict__ kvp,
    bf16* __restrict__ o)
{
    __shared__ __align__(16) bf16 Ks[64 * 64];      // [kv][64d], 16B-chunk XOR-swizzled
    __shared__ __align__(16) bf16 Vs[64 * 64];      // [kvb=16][dblk=4][4kv][16d]
    __shared__ __align__(16) bf16 Ps[4][16 * 72];   // per-wave P [q][kv], stride 72

    const int bid = blockIdx.x;
    const int idx = (bid & 7) * 256 + (bid >> 3);   // XCD-chunked (2048 % 8 == 0)
    const int bh = idx >> 5;
    const int qt = idx & 31;
    const int b = bh >> 4, h = bh & 15;

    const int t = threadIdx.x, lane = t & 63, w = t >> 6;
    const int r = lane & 15, g = lane >> 4;

    const size_t rowq = (size_t)b * NSEQ;

    // --- staging source offsets (kv0-independent part) ---
    size_t ksrc[2], vsrc[2];
#pragma unroll
    for (int c = 0; c < 2; c++) {
        const int p = c * 256 + t;                  // dest 16B-chunk index
        // K: LDS chunk (krow, ccol) holds global chunk (krow, ccol ^ (krow&7))
        const int krow = p >> 3;
        const int kcol = (p & 7) ^ (krow & 7);
        ksrc[c] = (size_t)(rowq + krow) * (2 * F_DIM) + h * HD + kcol * 8;
        // V: [kvb][dblk][4kv][16d] subtile permutation
        const int kvb = p >> 5, dblk = (p >> 3) & 3;
        const int kvl = (p & 7) >> 1, d8 = p & 1;
        vsrc[c] = (size_t)(rowq + kvb * 4 + kvl) * (2 * F_DIM) + F_DIM + h * HD
                  + dblk * 16 + d8 * 8;
    }
    bf16* kdst0 = Ks + (0 * 256 + (t & ~63)) * 8;   // wave-uniform dest bases
    bf16* kdst1 = Ks + (1 * 256 + (t & ~63)) * 8;
    bf16* vdst0 = Vs + (0 * 256 + (t & ~63)) * 8;
    bf16* vdst1 = Vs + (1 * 256 + (t & ~63)) * 8;

    // --- Q fragments (B-operand: lane holds Q[q=r][d = kk*32 + g*8 ..]) ---
    const int q0 = qt * 64 + w * 16;
    bf16x8 qf[2];
#pragma unroll
    for (int kk = 0; kk < 2; kk++)
        qf[kk] = *(const bf16x8*)(q + (rowq + q0 + r) * F_DIM + h * HD + kk * 32 + g * 8);

    f32x4 oacc[4];
#pragma unroll
    for (int i = 0; i < 4; i++) oacc[i] = (f32x4){0.f, 0.f, 0.f, 0.f};
    float m_r = -1e30f, l_r = 0.f;

    // tr_read per-lane base: group g reads subtiles kvb0 = kk*8 + g*2 (+kk imm)
    const unsigned va = lds_addr(Vs) + (unsigned)(g * 1024 + r * 8);

    for (int kv0 = 0; kv0 < NSEQ; kv0 += 64) {
        const size_t koff = (size_t)kv0 * (2 * F_DIM);
        __syncthreads();                            // prev tile fully consumed
        gload_lds16(kvp + ksrc[0] + koff, kdst0);
        gload_lds16(kvp + ksrc[1] + koff, kdst1);
        gload_lds16(kvp + vsrc[0] + koff, vdst0);
        gload_lds16(kvp + vsrc[1] + koff, vdst1);
        __syncthreads();                            // barrier drains vmcnt

        // --- S^T = K * Q^T : lane holds S[kv = nt*16 + g*4 + j][q = r] ---
        f32x4 s4[4];
#pragma unroll
        for (int nt = 0; nt < 4; nt++) s4[nt] = (f32x4){0.f, 0.f, 0.f, 0.f};
#pragma unroll
        for (int kk = 0; kk < 2; kk++) {
#pragma unroll
            for (int nt = 0; nt < 4; nt++) {
                const unsigned lb = (unsigned)((nt * 16 + r) * 128 + kk * 64 + g * 16)
                                    ^ (unsigned)((r & 7) << 4);
                bf16x8 kf = *(const bf16x8*)((const char*)Ks + lb);
                s4[nt] = __builtin_amdgcn_mfma_f32_16x16x32_bf16(kf, qf[kk], s4[nt], 0, 0, 0);
            }
        }

        // --- online softmax, lane-parallel (q = r) ---
        float mx = s4[0][0];
#pragma unroll
        for (int nt = 0; nt < 4; nt++)
#pragma unroll
            for (int j = 0; j < 4; j++) mx = fmaxf(mx, s4[nt][j]);
        mx = fmaxf(mx, __shfl_xor(mx, 16));
        mx = fmaxf(mx, __shfl_xor(mx, 32));
        const float mnew = fmaxf(m_r, mx);
        const float alpha = __expf(m_r - mnew);
        float ps = 0.f;
#pragma unroll
        for (int nt = 0; nt < 4; nt++)
#pragma unroll
            for (int j = 0; j < 4; j++) {
                const float pp = __expf(s4[nt][j] - mnew);
                s4[nt][j] = pp;
                ps += pp;
            }
        ps += __shfl_xor(ps, 16);
        ps += __shfl_xor(ps, 32);
        l_r = l_r * alpha + ps;
        m_r = mnew;

        // --- P -> per-wave LDS (8B writes; wave-local, no barrier) ---
#pragma unroll
        for (int nt = 0; nt < 4; nt++) {
            bf16x4 pb = { (bf16)s4[nt][0], (bf16)s4[nt][1],
                          (bf16)s4[nt][2], (bf16)s4[nt][3] };
            *(bf16x4*)&Ps[w][r * 72 + nt * 16 + g * 4] = pb;
        }

        // --- rescale O (lane holds O[q = g*4+j][d = ntd*16 + r]) ---
#pragma unroll
        for (int j = 0; j < 4; j++) {
            const float aj = __shfl(alpha, g * 4 + j);
#pragma unroll
            for (int ntd = 0; ntd < 4; ntd++) oacc[ntd][j] *= aj;
        }

        // --- read P as A-operand ---
        bf16x8 pf[2];
#pragma unroll
        for (int kk = 0; kk < 2; kk++)
            pf[kk] = *(const bf16x8*)&Ps[w][r * 72 + kk * 32 + g * 8];

        // --- V^T fragments via per-lane-addressed hardware transpose read ---
        u32x2 vt[4][2][2];
#pragma unroll
        for (int ntd = 0; ntd < 4; ntd++)
#pragma unroll
            for (int kk = 0; kk < 2; kk++) {
                const unsigned a = va + (unsigned)(kk * 4096 + ntd * 128);
                asm volatile("ds_read_b64_tr_b16 %0, %2\n\t"
                             "ds_read_b64_tr_b16 %1, %2 offset:512"
                             : "=&v"(vt[ntd][kk][0]), "=&v"(vt[ntd][kk][1])
                             : "v"(a));
            }
        asm volatile("s_waitcnt lgkmcnt(0)" ::: "memory");
        __builtin_amdgcn_sched_barrier(0);

        // --- O += P V ---
#pragma unroll
        for (int ntd = 0; ntd < 4; ntd++)
#pragma unroll
            for (int kk = 0; kk < 2; kk++) {
                union { u32x2 h[2]; bf16x8 v; } u;
                u.h[0] = vt[ntd][kk][0];
                u.h[1] = vt[ntd][kk][1];
                oacc[ntd] = __builtin_amdgcn_mfma_f32_16x16x32_bf16(pf[kk], u.v, oacc[ntd], 0, 0, 0);
            }
    }

    // --- epilogue: normalize + store ---
    float rl[4];
#pragma unroll
    for (int j = 0; j < 4; j++) {
        const float lj = __shfl(l_r, g * 4 + j);
        rl[j] = 1.0f / lj;
    }
#pragma unroll
    for (int ntd = 0; ntd < 4; ntd++)
#pragma unroll
        for (int j = 0; j < 4; j++) {
            const int row = q0 + g * 4 + j;
            o[(rowq + row) * F_DIM + h * HD + ntd * 16 + r] =
                (bf16)(oacc[ntd][j] * rl[j]);
        }
}

// ---------------------------------------------------------------------------
extern "C" void kernel_launch(void* const* d_in, const int* in_sizes, int n_in,
                              void* d_out, int out_size, void* d_ws, size_t ws_size,
                              hipStream_t stream)
{
    const float* x     = (const float*)d_in[0];
    const float* Wq    = (const float*)d_in[1];
    const float* Wkv   = (const float*)d_in[2];
    const float* Wo    = (const float*)d_in[3];
    const float* ln_g  = (const float*)d_in[4];
    const float* ln_b  = (const float*)d_in[5];
    const float* lnc_g = (const float*)d_in[6];
    const float* lnc_b = (const float*)d_in[7];
    float* out = (float*)d_out;

    bf16* xn   = (bf16*)d_ws;
    bf16* cn   = xn  + (size_t)MROWS * F_DIM;
    bf16* qb   = cn  + (size_t)MROWS * F_DIM;
    bf16* kvb  = qb  + (size_t)MROWS * F_DIM;
    bf16* wqb  = kvb + (size_t)MROWS * 2 * F_DIM;
    bf16* wkvb = wqb + (size_t)F_DIM * F_DIM;
    bf16* wob  = wkvb + (size_t)2 * F_DIM * F_DIM;
    bf16* ao   = xn;  // xn dead after q-GEMM

    ln2_kernel<<<dim3(MROWS), dim3(256), 0, stream>>>(x, ln_g, ln_b, lnc_g, lnc_b, xn, cn);

    cvt_kernel<<<dim3((F_DIM * F_DIM / 4 + 255) / 256), dim3(256), 0, stream>>>(Wq, wqb, F_DIM * F_DIM / 4);
    cvt_kernel<<<dim3((2 * F_DIM * F_DIM / 4 + 255) / 256), dim3(256), 0, stream>>>(Wkv, wkvb, 2 * F_DIM * F_DIM / 4);
    cvt_kernel<<<dim3((F_DIM * F_DIM / 4 + 255) / 256), dim3(256), 0, stream>>>(Wo, wob, F_DIM * F_DIM / 4);

    // q = (xn * Wq^T) * 0.125   (attention scale folded in; 2^-3 is exact)
    gemm_bt<0><<<dim3(F_DIM / 128, MROWS / 128), dim3(256), 0, stream>>>(
        xn, wqb, qb, nullptr, nullptr, MROWS, F_DIM, F_DIM, 0.125f);
    // kv = cn * Wkv^T
    gemm_bt<0><<<dim3(2 * F_DIM / 128, MROWS / 128), dim3(256), 0, stream>>>(
        cn, wkvb, kvb, nullptr, nullptr, MROWS, 2 * F_DIM, F_DIM, 1.0f);
    // attention
    attn_kernel<<<dim3(NSEQ / 64 * NB * NH), dim3(256), 0, stream>>>(qb, kvb, ao);
    // out = ao * Wo^T + x
    gemm_bt<1><<<dim3(F_DIM / 128, MROWS / 128), dim3(256), 0, stream>>>(
        ao, wob, nullptr, out, x, MROWS, F_DIM, F_DIM, 1.0f);
}